// Round 4
// baseline (251.308 us; speedup 1.0000x reference)
//
#include <hip/hip_runtime.h>

#define BB   2
#define CIN  8
#define COUT 16
#define HH   512
#define WW   1024
#define KK   9
#define NPIX (HH*WW)

typedef unsigned int u32;
typedef float f32x4 __attribute__((ext_vector_type(4)));

// fp32 -> bf16 bits, round-nearest-even
__device__ __forceinline__ u32 f2bf(float f) {
  u32 u = __float_as_uint(f);
  return (u + 0x7fffu + ((u >> 16) & 1u)) >> 16;
}
__device__ __forceinline__ float bflo(u32 u) { return __uint_as_float(u << 16); }
__device__ __forceinline__ float bfhi(u32 u) { return __uint_as_float(u & 0xffff0000u); }
__device__ __forceinline__ u32 comp4(uint4 v, int j) {
  return j == 0 ? v.x : j == 1 ? v.y : j == 2 ? v.z : v.w;
}

// x [B][C][H][W] fp32 -> xT [pixel][B][C] bf16 packed as u32 pairs.
// One thread handles 4 consecutive pixels (float4 in, 128B contiguous out).
__global__ __launch_bounds__(256) void xpose_k(const float* __restrict__ x,
                                               u32* __restrict__ xT) {
  int q = blockIdx.x * 256 + threadIdx.x;   // quad of pixels
  if (q >= NPIX / 4) return;
  u32 pk[4][BB][4];                          // [pix][b][chpair]
  #pragma unroll
  for (int b = 0; b < BB; ++b) {
    #pragma unroll
    for (int j = 0; j < 4; ++j) {
      float4 f0 = ((const float4*)(x + (size_t)(b * CIN + 2 * j    ) * NPIX))[q];
      float4 f1 = ((const float4*)(x + (size_t)(b * CIN + 2 * j + 1) * NPIX))[q];
      pk[0][b][j] = f2bf(f0.x) | (f2bf(f1.x) << 16);
      pk[1][b][j] = f2bf(f0.y) | (f2bf(f1.y) << 16);
      pk[2][b][j] = f2bf(f0.z) | (f2bf(f1.z) << 16);
      pk[3][b][j] = f2bf(f0.w) | (f2bf(f1.w) << 16);
    }
  }
  #pragma unroll
  for (int pix = 0; pix < 4; ++pix)
    #pragma unroll
    for (int b = 0; b < BB; ++b) {
      uint4 v; v.x = pk[pix][b][0]; v.y = pk[pix][b][1];
      v.z = pk[pix][b][2]; v.w = pk[pix][b][3];
      ((uint4*)xT)[(size_t)(q * 4 + pix) * 2 + b] = v;
    }
}

// Software-pipelined gather+FMA. One thread = one pixel, both batches, 16 outputs.
__global__ __launch_bounds__(256) void mconv2_k(const u32* __restrict__ xT,
                                                const float* __restrict__ sm,
                                                const float* __restrict__ weight,
                                                const float* __restrict__ bias,
                                                float* __restrict__ out) {
  __shared__ float sml[256 * KK * 2];              // block's sample coords, 18.4 KB
  __shared__ float wlds[KK * CIN * COUT];          // [k][c][o], 4.6 KB

  int tid = threadIdx.x;
  {
    const f32x4* g = (const f32x4*)(sm + (size_t)blockIdx.x * 256 * KK * 2);
    f32x4* l = (f32x4*)sml;
    for (int i = tid; i < 256 * KK * 2 / 4; i += 256)
      l[i] = __builtin_nontemporal_load(g + i);
  }
  for (int i = tid; i < KK * CIN * COUT; i += 256) {
    int k = i >> 7, c = (i >> 4) & 7, o = i & 15;
    wlds[i] = weight[(o * CIN + c) * KK + k];
  }
  __syncthreads();

  int p = blockIdx.x * 256 + tid;                  // grid is exactly NPIX/256

  float acc0[COUT], acc1[COUT];
  #pragma unroll
  for (int o = 0; o < COUT; ++o) { float bv = bias[o]; acc0[o] = bv; acc1[o] = bv; }

  const uint4* xt4 = (const uint4*)xT;

  // issue the 8 gather loads for sample k into v[8]  ([b0 c00,c01,c10,c11 | b1 ...])
  auto LOADK = [&](int k, uint4 (&v)[8]) {
    float px = sml[tid * 18 + k * 2], py = sml[tid * 18 + k * 2 + 1];
    int x0 = min(max((int)floorf(px), 0), WW - 1);
    int y0 = min(max((int)floorf(py), 0), HH - 1);
    int x1 = min(x0 + 1, WW - 1), y1 = min(y0 + 1, HH - 1);
    int r0 = y0 * WW, r1 = y1 * WW;
    v[0] = xt4[(size_t)(r0 + x0) * 2];     v[1] = xt4[(size_t)(r0 + x1) * 2];
    v[2] = xt4[(size_t)(r1 + x0) * 2];     v[3] = xt4[(size_t)(r1 + x1) * 2];
    v[4] = xt4[(size_t)(r0 + x0) * 2 + 1]; v[5] = xt4[(size_t)(r0 + x1) * 2 + 1];
    v[6] = xt4[(size_t)(r1 + x0) * 2 + 1]; v[7] = xt4[(size_t)(r1 + x1) * 2 + 1];
  };

  // consume sample k: bilinear combine + 256 FMAs into acc
  auto CONS = [&](int k, uint4 (&v)[8]) {
    float px = sml[tid * 18 + k * 2], py = sml[tid * 18 + k * 2 + 1];
    float x0f = floorf(px), y0f = floorf(py);
    float wx = px - x0f, wy = py - y0f;
    float w00 = (1.f - wy) * (1.f - wx), w01 = (1.f - wy) * wx;
    float w10 = wy * (1.f - wx),         w11 = wy * wx;
    const float4* w4 = (const float4*)&wlds[k * (CIN * COUT)];

    float sv0[8];
    #pragma unroll
    for (int j = 0; j < 4; ++j) {
      u32 a00 = comp4(v[0], j), a01 = comp4(v[1], j);
      u32 a10 = comp4(v[2], j), a11 = comp4(v[3], j);
      sv0[2*j]   = w00*bflo(a00) + w01*bflo(a01) + w10*bflo(a10) + w11*bflo(a11);
      sv0[2*j+1] = w00*bfhi(a00) + w01*bfhi(a01) + w10*bfhi(a10) + w11*bfhi(a11);
    }
    #pragma unroll
    for (int c = 0; c < 8; ++c) {
      float s0 = sv0[c];
      #pragma unroll
      for (int og = 0; og < 4; ++og) {
        float4 wv = w4[c * 4 + og];
        acc0[og*4+0] += s0 * wv.x; acc0[og*4+1] += s0 * wv.y;
        acc0[og*4+2] += s0 * wv.z; acc0[og*4+3] += s0 * wv.w;
      }
    }
    float sv1[8];
    #pragma unroll
    for (int j = 0; j < 4; ++j) {
      u32 b00 = comp4(v[4], j), b01 = comp4(v[5], j);
      u32 b10 = comp4(v[6], j), b11 = comp4(v[7], j);
      sv1[2*j]   = w00*bflo(b00) + w01*bflo(b01) + w10*bflo(b10) + w11*bflo(b11);
      sv1[2*j+1] = w00*bfhi(b00) + w01*bfhi(b01) + w10*bfhi(b10) + w11*bfhi(b11);
    }
    #pragma unroll
    for (int c = 0; c < 8; ++c) {
      float s1 = sv1[c];
      #pragma unroll
      for (int og = 0; og < 4; ++og) {
        float4 wv = w4[c * 4 + og];
        acc1[og*4+0] += s1 * wv.x; acc1[og*4+1] += s1 * wv.y;
        acc1[og*4+2] += s1 * wv.z; acc1[og*4+3] += s1 * wv.w;
      }
    }
  };

  uint4 va[8], vb[8];
  // depth-2 ping-pong pipeline, fully static
  LOADK(0, va); LOADK(1, vb);
  CONS(0, va);  LOADK(2, va);
  CONS(1, vb);  LOADK(3, vb);
  CONS(2, va);  LOADK(4, va);
  CONS(3, vb);  LOADK(5, vb);
  CONS(4, va);  LOADK(6, va);
  CONS(5, vb);  LOADK(7, vb);
  CONS(6, va);  LOADK(8, va);
  CONS(7, vb);
  CONS(8, va);

  #pragma unroll
  for (int o = 0; o < COUT; ++o) {
    __builtin_nontemporal_store(acc0[o], &out[(size_t)(0 * COUT + o) * NPIX + p]);
    __builtin_nontemporal_store(acc1[o], &out[(size_t)(1 * COUT + o) * NPIX + p]);
  }
}

// fallback if workspace too small: gather directly from fp32 x [B][C][H][W]
__global__ __launch_bounds__(256) void mconv_direct_k(const float* __restrict__ x,
                                                      const float* __restrict__ sm,
                                                      const float* __restrict__ weight,
                                                      const float* __restrict__ bias,
                                                      float* __restrict__ out) {
  __shared__ float wlds[KK * CIN * COUT];
  int tid = threadIdx.x;
  for (int i = tid; i < KK * CIN * COUT; i += 256) {
    int k = i >> 7, c = (i >> 4) & 7, o = i & 15;
    wlds[i] = weight[(o * CIN + c) * KK + k];
  }
  __syncthreads();

  int p = blockIdx.x * 256 + tid;
  if (p >= NPIX) return;

  float acc[2][COUT];
  #pragma unroll
  for (int o = 0; o < COUT; ++o) { float bv = bias[o]; acc[0][o] = bv; acc[1][o] = bv; }

  const float2* smp = (const float2*)sm;

  for (int k = 0; k < KK; ++k) {
    float2 s = smp[(size_t)p * KK + k];
    float x0f = floorf(s.x), y0f = floorf(s.y);
    float wx = s.x - x0f, wy = s.y - y0f;
    int x0 = min(max((int)x0f, 0), WW - 1);
    int y0 = min(max((int)y0f, 0), HH - 1);
    int x1 = min(x0 + 1, WW - 1), y1 = min(y0 + 1, HH - 1);
    float w00 = (1.f - wy) * (1.f - wx), w01 = (1.f - wy) * wx;
    float w10 = wy * (1.f - wx),         w11 = wy * wx;

    float sv[2][8];
    #pragma unroll
    for (int b = 0; b < 2; ++b) {
      #pragma unroll
      for (int c = 0; c < 8; ++c) {
        const float* xp = x + (size_t)(b * CIN + c) * NPIX;
        float v00 = xp[y0 * WW + x0], v01 = xp[y0 * WW + x1];
        float v10 = xp[y1 * WW + x0], v11 = xp[y1 * WW + x1];
        sv[b][c] = w00 * v00 + w01 * v01 + w10 * v10 + w11 * v11;
      }
    }

    const float4* w4 = (const float4*)&wlds[k * (CIN * COUT)];
    #pragma unroll
    for (int c = 0; c < 8; ++c) {
      float s0 = sv[0][c], s1 = sv[1][c];
      #pragma unroll
      for (int og = 0; og < 4; ++og) {
        float4 wv = w4[c * 4 + og];
        acc[0][og*4+0] += s0 * wv.x; acc[1][og*4+0] += s1 * wv.x;
        acc[0][og*4+1] += s0 * wv.y; acc[1][og*4+1] += s1 * wv.y;
        acc[0][og*4+2] += s0 * wv.z; acc[1][og*4+2] += s1 * wv.z;
        acc[0][og*4+3] += s0 * wv.w; acc[1][og*4+3] += s1 * wv.w;
      }
    }
  }

  #pragma unroll
  for (int b = 0; b < 2; ++b)
    #pragma unroll
    for (int o = 0; o < COUT; ++o)
      out[(size_t)(b * COUT + o) * NPIX + p] = acc[b][o];
}

extern "C" void kernel_launch(void* const* d_in, const int* in_sizes, int n_in,
                              void* d_out, int out_size, void* d_ws, size_t ws_size,
                              hipStream_t stream) {
  const float* x      = (const float*)d_in[0];
  const float* sm     = (const float*)d_in[1];
  const float* weight = (const float*)d_in[2];
  const float* bias   = (const float*)d_in[3];
  float* out = (float*)d_out;

  const size_t need = (size_t)NPIX * (BB * CIN) * sizeof(unsigned short);  // 16 MB xT
  if (ws_size >= need) {
    u32* xT = (u32*)d_ws;
    hipLaunchKernelGGL(xpose_k, dim3(NPIX / 4 / 256), dim3(256), 0, stream, x, xT);
    hipLaunchKernelGGL(mconv2_k, dim3(NPIX / 256), dim3(256), 0, stream,
                       xT, sm, weight, bias, out);
  } else {
    hipLaunchKernelGGL(mconv_direct_k, dim3((NPIX + 255) / 256), dim3(256), 0, stream,
                       x, sm, weight, bias, out);
  }
}

// Round 5
// 202.385 us; speedup vs baseline: 1.2417x; 1.2417x over previous
//
#include <hip/hip_runtime.h>

#define BB   2
#define CIN  8
#define COUT 16
#define HH   512
#define WW   1024
#define KK   9
#define NPIX (HH*WW)
#define COPY4 (1u << 20)   // uint4 elements per 16MB copy

typedef unsigned int u32;
typedef float f32x4 __attribute__((ext_vector_type(4)));

#define SB() __builtin_amdgcn_sched_barrier(0)

// fp32 -> bf16 bits, round-nearest-even
__device__ __forceinline__ u32 f2bf(float f) {
  u32 u = __float_as_uint(f);
  return (u + 0x7fffu + ((u >> 16) & 1u)) >> 16;
}
__device__ __forceinline__ float bflo(u32 u) { return __uint_as_float(u << 16); }
__device__ __forceinline__ float bfhi(u32 u) { return __uint_as_float(u & 0xffff0000u); }
__device__ __forceinline__ u32 comp4(uint4 v, int j) {
  return j == 0 ? v.x : j == 1 ? v.y : j == 2 ? v.z : v.w;
}

// x [B][C][H][W] fp32 -> pair-interleaved bf16 copies.
// copyA uint4 idx for (pixel p, batch b):  (p>>1)*4 + (p&1)*2 + b
// copyB holds pixels shifted by one: idx((p-1)) + COPY4   (w in [1,1022])
// Each uint4 = 8 channels bf16 of one (pixel,batch).
__global__ __launch_bounds__(256) void xpose2_k(const float* __restrict__ x,
                                                uint4* __restrict__ xt4,
                                                int write_b) {
  int q = blockIdx.x * 256 + threadIdx.x;   // quad of pixels
  if (q >= NPIX / 4) return;
  u32 pk[4][BB][4];                          // [pix][b][chpair]
  #pragma unroll
  for (int b = 0; b < BB; ++b) {
    #pragma unroll
    for (int j = 0; j < 4; ++j) {
      float4 f0 = ((const float4*)(x + (size_t)(b * CIN + 2 * j    ) * NPIX))[q];
      float4 f1 = ((const float4*)(x + (size_t)(b * CIN + 2 * j + 1) * NPIX))[q];
      pk[0][b][j] = f2bf(f0.x) | (f2bf(f1.x) << 16);
      pk[1][b][j] = f2bf(f0.y) | (f2bf(f1.y) << 16);
      pk[2][b][j] = f2bf(f0.z) | (f2bf(f1.z) << 16);
      pk[3][b][j] = f2bf(f0.w) | (f2bf(f1.w) << 16);
    }
  }
  #pragma unroll
  for (int pix = 0; pix < 4; ++pix) {
    int p = q * 4 + pix;
    int w = p & (WW - 1);
    #pragma unroll
    for (int b = 0; b < BB; ++b) {
      uint4 v; v.x = pk[pix][b][0]; v.y = pk[pix][b][1];
      v.z = pk[pix][b][2]; v.w = pk[pix][b][3];
      xt4[(p >> 1) * 4 + (p & 1) * 2 + b] = v;
      if (write_b && w >= 1 && w <= WW - 2) {
        int pp = p - 1;
        xt4[COPY4 + (pp >> 1) * 4 + (pp & 1) * 2 + b] = v;
      }
    }
  }
}

// One thread = one (pixel, batch). Depth-3 pinned software pipeline.
template <bool DUAL>
__global__ __launch_bounds__(256, 5) void mconv3_k(const uint4* __restrict__ xt4,
                                                   const float* __restrict__ sm,
                                                   const float* __restrict__ weight,
                                                   const float* __restrict__ bias,
                                                   float* __restrict__ out) {
  __shared__ float sml[128 * KK * 2];              // block's 128 pixels' coords, 9.2 KB
  __shared__ float wlds[KK * CIN * COUT];          // [k][c][o], 4.6 KB

  int tid = threadIdx.x;
  {
    const f32x4* g = (const f32x4*)(sm + (size_t)blockIdx.x * 128 * KK * 2);
    f32x4* l = (f32x4*)sml;
    for (int i = tid; i < 128 * KK * 2 / 4; i += 256) l[i] = g[i];
  }
  for (int i = tid; i < KK * CIN * COUT; i += 256) {
    int k = i >> 7, c = (i >> 4) & 7, o = i & 15;
    wlds[i] = weight[(o * CIN + c) * KK + k];
  }
  __syncthreads();

  const int pl = tid & 127;        // pixel within block
  const int b  = tid >> 7;         // batch
  const int p  = blockIdx.x * 128 + pl;

  float acc[COUT];
  #pragma unroll
  for (int o = 0; o < COUT; ++o) acc[o] = bias[o];

  // issue the 4 corner loads (this thread's batch) for sample k
  auto LOADK = [&](int k, uint4 (&v)[4]) {
    float2 s = ((const float2*)sml)[pl * KK + k];
    int x0 = min(max((int)floorf(s.x), 0), WW - 2);
    int y0 = min(max((int)floorf(s.y), 0), HH - 2);
    if (DUAL) {
      int odd = x0 & 1;
      const uint4* cp = xt4 + (odd ? COPY4 : 0u);
      int i0 = (y0 * (WW / 2) + ((x0 - odd) >> 1)) * 4 + b;
      v[0] = cp[i0];        v[1] = cp[i0 + 2];          // (y0,x0) (y0,x1)
      v[2] = cp[i0 + 2048]; v[3] = cp[i0 + 2048 + 2];   // (y1,x0) (y1,x1)
    } else {
      int x1 = x0 + 1;
      int iL = (y0 * (WW / 2) + (x0 >> 1)) * 4 + ((x0 & 1) << 1) + b;
      int iR = (y0 * (WW / 2) + (x1 >> 1)) * 4 + ((x1 & 1) << 1) + b;
      v[0] = xt4[iL];        v[1] = xt4[iR];
      v[2] = xt4[iL + 2048]; v[3] = xt4[iR + 2048];
    }
  };

  // consume sample k: bilinear combine + 128 FMAs into acc
  auto CONS = [&](int k, uint4 (&v)[4]) {
    float2 s = ((const float2*)sml)[pl * KK + k];
    float x0f = floorf(s.x), y0f = floorf(s.y);
    float wx = s.x - x0f, wy = s.y - y0f;
    float w00 = (1.f - wy) * (1.f - wx), w01 = (1.f - wy) * wx;
    float w10 = wy * (1.f - wx),         w11 = wy * wx;
    const float4* w4 = (const float4*)&wlds[k * (CIN * COUT)];

    float sv[8];
    #pragma unroll
    for (int j = 0; j < 4; ++j) {
      u32 a00 = comp4(v[0], j), a01 = comp4(v[1], j);
      u32 a10 = comp4(v[2], j), a11 = comp4(v[3], j);
      sv[2*j]   = w00*bflo(a00) + w01*bflo(a01) + w10*bflo(a10) + w11*bflo(a11);
      sv[2*j+1] = w00*bfhi(a00) + w01*bfhi(a01) + w10*bfhi(a10) + w11*bfhi(a11);
    }
    #pragma unroll
    for (int c = 0; c < 8; ++c) {
      float s0 = sv[c];
      #pragma unroll
      for (int og = 0; og < 4; ++og) {
        float4 wv = w4[c * 4 + og];
        acc[og*4+0] += s0 * wv.x; acc[og*4+1] += s0 * wv.y;
        acc[og*4+2] += s0 * wv.z; acc[og*4+3] += s0 * wv.w;
      }
    }
  };

  uint4 va[4], vb[4], vc[4];
  // depth-3, order pinned with sched_barrier(0)
  LOADK(0, va); SB();
  LOADK(1, vb); SB();
  LOADK(2, vc); SB();
  CONS(0, va);  SB(); LOADK(3, va); SB();
  CONS(1, vb);  SB(); LOADK(4, vb); SB();
  CONS(2, vc);  SB(); LOADK(5, vc); SB();
  CONS(3, va);  SB(); LOADK(6, va); SB();
  CONS(4, vb);  SB(); LOADK(7, vb); SB();
  CONS(5, vc);  SB(); LOADK(8, vc); SB();
  CONS(6, va);  SB();
  CONS(7, vb);  SB();
  CONS(8, vc);

  #pragma unroll
  for (int o = 0; o < COUT; ++o)
    __builtin_nontemporal_store(acc[o], &out[(size_t)(b * COUT + o) * NPIX + p]);
}

// fallback if workspace too small: gather directly from fp32 x [B][C][H][W]
__global__ __launch_bounds__(256) void mconv_direct_k(const float* __restrict__ x,
                                                      const float* __restrict__ sm,
                                                      const float* __restrict__ weight,
                                                      const float* __restrict__ bias,
                                                      float* __restrict__ out) {
  __shared__ float wlds[KK * CIN * COUT];
  int tid = threadIdx.x;
  for (int i = tid; i < KK * CIN * COUT; i += 256) {
    int k = i >> 7, c = (i >> 4) & 7, o = i & 15;
    wlds[i] = weight[(o * CIN + c) * KK + k];
  }
  __syncthreads();

  int p = blockIdx.x * 256 + tid;
  if (p >= NPIX) return;

  float acc[2][COUT];
  #pragma unroll
  for (int o = 0; o < COUT; ++o) { float bv = bias[o]; acc[0][o] = bv; acc[1][o] = bv; }

  const float2* smp = (const float2*)sm;

  for (int k = 0; k < KK; ++k) {
    float2 s = smp[(size_t)p * KK + k];
    float x0f = floorf(s.x), y0f = floorf(s.y);
    float wx = s.x - x0f, wy = s.y - y0f;
    int x0 = min(max((int)x0f, 0), WW - 1);
    int y0 = min(max((int)y0f, 0), HH - 1);
    int x1 = min(x0 + 1, WW - 1), y1 = min(y0 + 1, HH - 1);
    float w00 = (1.f - wy) * (1.f - wx), w01 = (1.f - wy) * wx;
    float w10 = wy * (1.f - wx),         w11 = wy * wx;

    float sv[2][8];
    #pragma unroll
    for (int b = 0; b < 2; ++b) {
      #pragma unroll
      for (int c = 0; c < 8; ++c) {
        const float* xp = x + (size_t)(b * CIN + c) * NPIX;
        float v00 = xp[y0 * WW + x0], v01 = xp[y0 * WW + x1];
        float v10 = xp[y1 * WW + x0], v11 = xp[y1 * WW + x1];
        sv[b][c] = w00 * v00 + w01 * v01 + w10 * v10 + w11 * v11;
      }
    }

    const float4* w4 = (const float4*)&wlds[k * (CIN * COUT)];
    #pragma unroll
    for (int c = 0; c < 8; ++c) {
      float s0 = sv[0][c], s1 = sv[1][c];
      #pragma unroll
      for (int og = 0; og < 4; ++og) {
        float4 wv = w4[c * 4 + og];
        acc[0][og*4+0] += s0 * wv.x; acc[1][og*4+0] += s1 * wv.x;
        acc[0][og*4+1] += s0 * wv.y; acc[1][og*4+1] += s1 * wv.y;
        acc[0][og*4+2] += s0 * wv.z; acc[1][og*4+2] += s1 * wv.z;
        acc[0][og*4+3] += s0 * wv.w; acc[1][og*4+3] += s1 * wv.w;
      }
    }
  }

  #pragma unroll
  for (int b = 0; b < 2; ++b)
    #pragma unroll
    for (int o = 0; o < COUT; ++o)
      out[(size_t)(b * COUT + o) * NPIX + p] = acc[b][o];
}

extern "C" void kernel_launch(void* const* d_in, const int* in_sizes, int n_in,
                              void* d_out, int out_size, void* d_ws, size_t ws_size,
                              hipStream_t stream) {
  const float* x      = (const float*)d_in[0];
  const float* sm     = (const float*)d_in[1];
  const float* weight = (const float*)d_in[2];
  const float* bias   = (const float*)d_in[3];
  float* out = (float*)d_out;

  const size_t oneCopy = (size_t)NPIX * (BB * CIN) * sizeof(unsigned short); // 16 MB
  if (ws_size >= 2 * oneCopy) {
    uint4* xt4 = (uint4*)d_ws;
    hipLaunchKernelGGL(xpose2_k, dim3(NPIX / 4 / 256), dim3(256), 0, stream,
                       x, xt4, 1);
    hipLaunchKernelGGL(mconv3_k<true>, dim3(NPIX / 128), dim3(256), 0, stream,
                       xt4, sm, weight, bias, out);
  } else if (ws_size >= oneCopy) {
    uint4* xt4 = (uint4*)d_ws;
    hipLaunchKernelGGL(xpose2_k, dim3(NPIX / 4 / 256), dim3(256), 0, stream,
                       x, xt4, 0);
    hipLaunchKernelGGL(mconv3_k<false>, dim3(NPIX / 128), dim3(256), 0, stream,
                       xt4, sm, weight, bias, out);
  } else {
    hipLaunchKernelGGL(mconv_direct_k, dim3((NPIX + 255) / 256), dim3(256), 0, stream,
                       x, sm, weight, bias, out);
  }
}

// Round 6
// 195.684 us; speedup vs baseline: 1.2843x; 1.0342x over previous
//
#include <hip/hip_runtime.h>

#define BB   2
#define CIN  8
#define COUT 16
#define HH   512
#define WW   1024
#define KK   9
#define NPIX (HH*WW)
#define COPY4 (1u << 20)   // uint4 elements per 16MB copy

typedef unsigned int u32;
typedef float f32x4 __attribute__((ext_vector_type(4)));

#define SB() __builtin_amdgcn_sched_barrier(0)

// fp32 -> bf16 bits, round-nearest-even
__device__ __forceinline__ u32 f2bf(float f) {
  u32 u = __float_as_uint(f);
  return (u + 0x7fffu + ((u >> 16) & 1u)) >> 16;
}
__device__ __forceinline__ float bflo(u32 u) { return __uint_as_float(u << 16); }
__device__ __forceinline__ float bfhi(u32 u) { return __uint_as_float(u & 0xffff0000u); }
__device__ __forceinline__ u32 comp4(uint4 v, int j) {
  return j == 0 ? v.x : j == 1 ? v.y : j == 2 ? v.z : v.w;
}

// ============ 4-copy 2D-parity layout ============
// copy (pyp,pxp): blocks of 2x2 pixels starting at rows {2*by+pyp}, cols {2*bx+pxp}.
// uint4 index = (pyp*2+pxp)<<20 + ((by*512+bx)*2 + b)*4 + dy*2 + dx
// One 64B block = 2y x 2x x 8ch bf16 of one batch; sibling batch is adjacent 64B.
__global__ __launch_bounds__(256) void xpose3_k(const float* __restrict__ x,
                                                uint4* __restrict__ xt4) {
  int q = blockIdx.x * 256 + threadIdx.x;      // x-pair index
  if (q >= NPIX / 2) return;
  int y = q >> 9, xp = q & 511;
  u32 pk[2][BB][4];                             // [pix-in-pair][b][chpair]
  #pragma unroll
  for (int b = 0; b < BB; ++b) {
    #pragma unroll
    for (int j = 0; j < 4; ++j) {
      float2 f0 = ((const float2*)(x + (size_t)(b * CIN + 2 * j    ) * NPIX + (size_t)y * WW))[xp];
      float2 f1 = ((const float2*)(x + (size_t)(b * CIN + 2 * j + 1) * NPIX + (size_t)y * WW))[xp];
      pk[0][b][j] = f2bf(f0.x) | (f2bf(f1.x) << 16);
      pk[1][b][j] = f2bf(f0.y) | (f2bf(f1.y) << 16);
    }
  }
  #pragma unroll
  for (int pi = 0; pi < 2; ++pi) {
    int xx = 2 * xp + pi;
    #pragma unroll
    for (int b = 0; b < BB; ++b) {
      uint4 v; v.x = pk[pi][b][0]; v.y = pk[pi][b][1];
      v.z = pk[pi][b][2]; v.w = pk[pi][b][3];
      #pragma unroll
      for (int pyp = 0; pyp < 2; ++pyp)
        #pragma unroll
        for (int pxp = 0; pxp < 2; ++pxp) {
          if (xx < pxp || y < pyp) continue;
          u32 idx = ((u32)(pyp * 2 + pxp) << 20)
                  + ((u32)(((y - pyp) >> 1) * 512 + ((xx - pxp) >> 1)) * 2 + (u32)b) * 4
                  + (u32)(((y - pyp) & 1) * 2 + ((xx - pxp) & 1));
          xt4[idx] = v;
        }
    }
  }
}

// One thread = one (pixel, batch). Each sample = 4 loads from ONE 64B block.
__global__ __launch_bounds__(256, 4) void mconv4_k(const uint4* __restrict__ xt4,
                                                   const float* __restrict__ sm,
                                                   const float* __restrict__ weight,
                                                   const float* __restrict__ bias,
                                                   float* __restrict__ out) {
  __shared__ float sml[128 * KK * 2];              // block's 128 pixels' coords
  __shared__ float wlds[KK * CIN * COUT];          // [k][c][o]

  int tid = threadIdx.x;
  {
    const f32x4* g = (const f32x4*)(sm + (size_t)blockIdx.x * 128 * KK * 2);
    f32x4* l = (f32x4*)sml;
    for (int i = tid; i < 128 * KK * 2 / 4; i += 256) l[i] = g[i];
  }
  for (int i = tid; i < KK * CIN * COUT; i += 256) {
    int k = i >> 7, c = (i >> 4) & 7, o = i & 15;
    wlds[i] = weight[(o * CIN + c) * KK + k];
  }
  __syncthreads();

  const int pl = tid & 127;        // pixel within block
  const int b  = tid >> 7;         // batch
  const int p  = blockIdx.x * 128 + pl;

  float acc[COUT];
  #pragma unroll
  for (int o = 0; o < COUT; ++o) acc[o] = bias[o];

  auto LOADK = [&](int k, uint4 (&v)[4]) {
    float2 s = ((const float2*)sml)[pl * KK + k];
    int x0 = min(max((int)floorf(s.x), 0), WW - 2);
    int y0 = min(max((int)floorf(s.y), 0), HH - 2);
    u32 idx = ((u32)((y0 & 1) * 2 + (x0 & 1)) << 20)
            + ((u32)((y0 >> 1) * 512 + (x0 >> 1)) * 2 + (u32)b) * 4;
    v[0] = xt4[idx];     v[1] = xt4[idx + 1];     // (y0,x0) (y0,x1)
    v[2] = xt4[idx + 2]; v[3] = xt4[idx + 3];     // (y1,x0) (y1,x1)
  };

  auto CONS = [&](int k, uint4 (&v)[4]) {
    float2 s = ((const float2*)sml)[pl * KK + k];
    float x0f = floorf(s.x), y0f = floorf(s.y);
    float wx = s.x - x0f, wy = s.y - y0f;
    float w00 = (1.f - wy) * (1.f - wx), w01 = (1.f - wy) * wx;
    float w10 = wy * (1.f - wx),         w11 = wy * wx;
    const float4* w4 = (const float4*)&wlds[k * (CIN * COUT)];

    float sv[8];
    #pragma unroll
    for (int j = 0; j < 4; ++j) {
      u32 a00 = comp4(v[0], j), a01 = comp4(v[1], j);
      u32 a10 = comp4(v[2], j), a11 = comp4(v[3], j);
      sv[2*j]   = w00*bflo(a00) + w01*bflo(a01) + w10*bflo(a10) + w11*bflo(a11);
      sv[2*j+1] = w00*bfhi(a00) + w01*bfhi(a01) + w10*bfhi(a10) + w11*bfhi(a11);
    }
    #pragma unroll
    for (int c = 0; c < 8; ++c) {
      float s0 = sv[c];
      #pragma unroll
      for (int og = 0; og < 4; ++og) {
        float4 wv = w4[c * 4 + og];
        acc[og*4+0] += s0 * wv.x; acc[og*4+1] += s0 * wv.y;
        acc[og*4+2] += s0 * wv.z; acc[og*4+3] += s0 * wv.w;
      }
    }
  };

  uint4 va[4], vb[4], vc[4];
  LOADK(0, va); SB();
  LOADK(1, vb); SB();
  LOADK(2, vc); SB();
  CONS(0, va);  SB(); LOADK(3, va); SB();
  CONS(1, vb);  SB(); LOADK(4, vb); SB();
  CONS(2, vc);  SB(); LOADK(5, vc); SB();
  CONS(3, va);  SB(); LOADK(6, va); SB();
  CONS(4, vb);  SB(); LOADK(7, vb); SB();
  CONS(5, vc);  SB(); LOADK(8, vc); SB();
  CONS(6, va);  SB();
  CONS(7, vb);  SB();
  CONS(8, vc);

  #pragma unroll
  for (int o = 0; o < COUT; ++o)
    __builtin_nontemporal_store(acc[o], &out[(size_t)(b * COUT + o) * NPIX + p]);
}

// ============ fallback: pair-interleaved single/dual copies (round-5 path) ============
__global__ __launch_bounds__(256) void xpose2_k(const float* __restrict__ x,
                                                uint4* __restrict__ xt4,
                                                int write_b) {
  int q = blockIdx.x * 256 + threadIdx.x;   // quad of pixels
  if (q >= NPIX / 4) return;
  u32 pk[4][BB][4];
  #pragma unroll
  for (int b = 0; b < BB; ++b) {
    #pragma unroll
    for (int j = 0; j < 4; ++j) {
      float4 f0 = ((const float4*)(x + (size_t)(b * CIN + 2 * j    ) * NPIX))[q];
      float4 f1 = ((const float4*)(x + (size_t)(b * CIN + 2 * j + 1) * NPIX))[q];
      pk[0][b][j] = f2bf(f0.x) | (f2bf(f1.x) << 16);
      pk[1][b][j] = f2bf(f0.y) | (f2bf(f1.y) << 16);
      pk[2][b][j] = f2bf(f0.z) | (f2bf(f1.z) << 16);
      pk[3][b][j] = f2bf(f0.w) | (f2bf(f1.w) << 16);
    }
  }
  #pragma unroll
  for (int pix = 0; pix < 4; ++pix) {
    int p = q * 4 + pix;
    int w = p & (WW - 1);
    #pragma unroll
    for (int b = 0; b < BB; ++b) {
      uint4 v; v.x = pk[pix][b][0]; v.y = pk[pix][b][1];
      v.z = pk[pix][b][2]; v.w = pk[pix][b][3];
      xt4[(p >> 1) * 4 + (p & 1) * 2 + b] = v;
      if (write_b && w >= 1 && w <= WW - 2) {
        int pp = p - 1;
        xt4[COPY4 + (pp >> 1) * 4 + (pp & 1) * 2 + b] = v;
      }
    }
  }
}

template <bool DUAL>
__global__ __launch_bounds__(256, 5) void mconv3_k(const uint4* __restrict__ xt4,
                                                   const float* __restrict__ sm,
                                                   const float* __restrict__ weight,
                                                   const float* __restrict__ bias,
                                                   float* __restrict__ out) {
  __shared__ float sml[128 * KK * 2];
  __shared__ float wlds[KK * CIN * COUT];

  int tid = threadIdx.x;
  {
    const f32x4* g = (const f32x4*)(sm + (size_t)blockIdx.x * 128 * KK * 2);
    f32x4* l = (f32x4*)sml;
    for (int i = tid; i < 128 * KK * 2 / 4; i += 256) l[i] = g[i];
  }
  for (int i = tid; i < KK * CIN * COUT; i += 256) {
    int k = i >> 7, c = (i >> 4) & 7, o = i & 15;
    wlds[i] = weight[(o * CIN + c) * KK + k];
  }
  __syncthreads();

  const int pl = tid & 127;
  const int b  = tid >> 7;
  const int p  = blockIdx.x * 128 + pl;

  float acc[COUT];
  #pragma unroll
  for (int o = 0; o < COUT; ++o) acc[o] = bias[o];

  auto LOADK = [&](int k, uint4 (&v)[4]) {
    float2 s = ((const float2*)sml)[pl * KK + k];
    int x0 = min(max((int)floorf(s.x), 0), WW - 2);
    int y0 = min(max((int)floorf(s.y), 0), HH - 2);
    if (DUAL) {
      int odd = x0 & 1;
      const uint4* cp = xt4 + (odd ? COPY4 : 0u);
      int i0 = (y0 * (WW / 2) + ((x0 - odd) >> 1)) * 4 + b;
      v[0] = cp[i0];        v[1] = cp[i0 + 2];
      v[2] = cp[i0 + 2048]; v[3] = cp[i0 + 2048 + 2];
    } else {
      int x1 = x0 + 1;
      int iL = (y0 * (WW / 2) + (x0 >> 1)) * 4 + ((x0 & 1) << 1) + b;
      int iR = (y0 * (WW / 2) + (x1 >> 1)) * 4 + ((x1 & 1) << 1) + b;
      v[0] = xt4[iL];        v[1] = xt4[iR];
      v[2] = xt4[iL + 2048]; v[3] = xt4[iR + 2048];
    }
  };

  auto CONS = [&](int k, uint4 (&v)[4]) {
    float2 s = ((const float2*)sml)[pl * KK + k];
    float x0f = floorf(s.x), y0f = floorf(s.y);
    float wx = s.x - x0f, wy = s.y - y0f;
    float w00 = (1.f - wy) * (1.f - wx), w01 = (1.f - wy) * wx;
    float w10 = wy * (1.f - wx),         w11 = wy * wx;
    const float4* w4 = (const float4*)&wlds[k * (CIN * COUT)];

    float sv[8];
    #pragma unroll
    for (int j = 0; j < 4; ++j) {
      u32 a00 = comp4(v[0], j), a01 = comp4(v[1], j);
      u32 a10 = comp4(v[2], j), a11 = comp4(v[3], j);
      sv[2*j]   = w00*bflo(a00) + w01*bflo(a01) + w10*bflo(a10) + w11*bflo(a11);
      sv[2*j+1] = w00*bfhi(a00) + w01*bfhi(a01) + w10*bfhi(a10) + w11*bfhi(a11);
    }
    #pragma unroll
    for (int c = 0; c < 8; ++c) {
      float s0 = sv[c];
      #pragma unroll
      for (int og = 0; og < 4; ++og) {
        float4 wv = w4[c * 4 + og];
        acc[og*4+0] += s0 * wv.x; acc[og*4+1] += s0 * wv.y;
        acc[og*4+2] += s0 * wv.z; acc[og*4+3] += s0 * wv.w;
      }
    }
  };

  uint4 va[4], vb[4], vc[4];
  LOADK(0, va); SB();
  LOADK(1, vb); SB();
  LOADK(2, vc); SB();
  CONS(0, va);  SB(); LOADK(3, va); SB();
  CONS(1, vb);  SB(); LOADK(4, vb); SB();
  CONS(2, vc);  SB(); LOADK(5, vc); SB();
  CONS(3, va);  SB(); LOADK(6, va); SB();
  CONS(4, vb);  SB(); LOADK(7, vb); SB();
  CONS(5, vc);  SB(); LOADK(8, vc); SB();
  CONS(6, va);  SB();
  CONS(7, vb);  SB();
  CONS(8, vc);

  #pragma unroll
  for (int o = 0; o < COUT; ++o)
    __builtin_nontemporal_store(acc[o], &out[(size_t)(b * COUT + o) * NPIX + p]);
}

// fallback if workspace too small: gather directly from fp32 x [B][C][H][W]
__global__ __launch_bounds__(256) void mconv_direct_k(const float* __restrict__ x,
                                                      const float* __restrict__ sm,
                                                      const float* __restrict__ weight,
                                                      const float* __restrict__ bias,
                                                      float* __restrict__ out) {
  __shared__ float wlds[KK * CIN * COUT];
  int tid = threadIdx.x;
  for (int i = tid; i < KK * CIN * COUT; i += 256) {
    int k = i >> 7, c = (i >> 4) & 7, o = i & 15;
    wlds[i] = weight[(o * CIN + c) * KK + k];
  }
  __syncthreads();

  int p = blockIdx.x * 256 + tid;
  if (p >= NPIX) return;

  float acc[2][COUT];
  #pragma unroll
  for (int o = 0; o < COUT; ++o) { float bv = bias[o]; acc[0][o] = bv; acc[1][o] = bv; }

  const float2* smp = (const float2*)sm;

  for (int k = 0; k < KK; ++k) {
    float2 s = smp[(size_t)p * KK + k];
    float x0f = floorf(s.x), y0f = floorf(s.y);
    float wx = s.x - x0f, wy = s.y - y0f;
    int x0 = min(max((int)x0f, 0), WW - 1);
    int y0 = min(max((int)y0f, 0), HH - 1);
    int x1 = min(x0 + 1, WW - 1), y1 = min(y0 + 1, HH - 1);
    float w00 = (1.f - wy) * (1.f - wx), w01 = (1.f - wy) * wx;
    float w10 = wy * (1.f - wx),         w11 = wy * wx;

    float sv[2][8];
    #pragma unroll
    for (int b = 0; b < 2; ++b) {
      #pragma unroll
      for (int c = 0; c < 8; ++c) {
        const float* xp = x + (size_t)(b * CIN + c) * NPIX;
        float v00 = xp[y0 * WW + x0], v01 = xp[y0 * WW + x1];
        float v10 = xp[y1 * WW + x0], v11 = xp[y1 * WW + x1];
        sv[b][c] = w00 * v00 + w01 * v01 + w10 * v10 + w11 * v11;
      }
    }

    const float4* w4 = (const float4*)&wlds[k * (CIN * COUT)];
    #pragma unroll
    for (int c = 0; c < 8; ++c) {
      float s0 = sv[0][c], s1 = sv[1][c];
      #pragma unroll
      for (int og = 0; og < 4; ++og) {
        float4 wv = w4[c * 4 + og];
        acc[0][og*4+0] += s0 * wv.x; acc[1][og*4+0] += s1 * wv.x;
        acc[0][og*4+1] += s0 * wv.y; acc[1][og*4+1] += s1 * wv.y;
        acc[0][og*4+2] += s0 * wv.z; acc[1][og*4+2] += s1 * wv.z;
        acc[0][og*4+3] += s0 * wv.w; acc[1][og*4+3] += s1 * wv.w;
      }
    }
  }

  #pragma unroll
  for (int b = 0; b < 2; ++b)
    #pragma unroll
    for (int o = 0; o < COUT; ++o)
      out[(size_t)(b * COUT + o) * NPIX + p] = acc[b][o];
}

extern "C" void kernel_launch(void* const* d_in, const int* in_sizes, int n_in,
                              void* d_out, int out_size, void* d_ws, size_t ws_size,
                              hipStream_t stream) {
  const float* x      = (const float*)d_in[0];
  const float* sm     = (const float*)d_in[1];
  const float* weight = (const float*)d_in[2];
  const float* bias   = (const float*)d_in[3];
  float* out = (float*)d_out;

  const size_t oneCopy = (size_t)COPY4 * sizeof(uint4);   // 16 MB
  uint4* xt4 = (uint4*)d_ws;
  if (ws_size >= 4 * oneCopy) {
    hipLaunchKernelGGL(xpose3_k, dim3(NPIX / 2 / 256), dim3(256), 0, stream, x, xt4);
    hipLaunchKernelGGL(mconv4_k, dim3(NPIX / 128), dim3(256), 0, stream,
                       xt4, sm, weight, bias, out);
  } else if (ws_size >= 2 * oneCopy) {
    hipLaunchKernelGGL(xpose2_k, dim3(NPIX / 4 / 256), dim3(256), 0, stream, x, xt4, 1);
    hipLaunchKernelGGL(mconv3_k<true>, dim3(NPIX / 128), dim3(256), 0, stream,
                       xt4, sm, weight, bias, out);
  } else if (ws_size >= oneCopy) {
    hipLaunchKernelGGL(xpose2_k, dim3(NPIX / 4 / 256), dim3(256), 0, stream, x, xt4, 0);
    hipLaunchKernelGGL(mconv3_k<false>, dim3(NPIX / 128), dim3(256), 0, stream,
                       xt4, sm, weight, bias, out);
  } else {
    hipLaunchKernelGGL(mconv_direct_k, dim3((NPIX + 255) / 256), dim3(256), 0, stream,
                       x, sm, weight, bias, out);
  }
}

// Round 7
// 166.068 us; speedup vs baseline: 1.5133x; 1.1783x over previous
//
#include <hip/hip_runtime.h>

#define BB   2
#define CIN  8
#define COUT 16
#define HH   512
#define WW   1024
#define KK   9
#define NPIX (HH*WW)
#define COPY4 (1u << 20)   // uint4 elements per 16MB copy

typedef unsigned int u32;
typedef float f32x4 __attribute__((ext_vector_type(4)));

#define SB() __builtin_amdgcn_sched_barrier(0)

// fp32 -> bf16 bits, round-nearest-even
__device__ __forceinline__ u32 f2bf(float f) {
  u32 u = __float_as_uint(f);
  return (u + 0x7fffu + ((u >> 16) & 1u)) >> 16;
}
__device__ __forceinline__ float bflo(u32 u) { return __uint_as_float(u << 16); }
__device__ __forceinline__ float bfhi(u32 u) { return __uint_as_float(u & 0xffff0000u); }
__device__ __forceinline__ u32 comp4(uint4 v, int j) {
  return j == 0 ? v.x : j == 1 ? v.y : j == 2 ? v.z : v.w;
}

// ============ 4-copy 2D-parity layout ============
// copy (pyp,pxp): 2x2-pixel blocks starting at rows 2*by+pyp, cols 2*bx+pxp.
// uint4 index = (pyp*2+pxp)<<20 + ((by*512+bx)*2 + b)*4 + dy*2 + dx
// One 64B block = 2y x 2x x 8ch bf16 of one batch; sibling batch adjacent 64B.

// One thread per (by,bx): reads its 3x3 fp32 pixel neighborhood, writes
// COMPLETE 64B blocks for all 4 copies x 2 batches, fully coalesced.
__global__ __launch_bounds__(256) void xpose3b_k(const float* __restrict__ x,
                                                 uint4* __restrict__ xt4) {
  int t = blockIdx.x * 256 + threadIdx.x;
  if (t >= (HH / 2) * (WW / 2)) return;
  int by = t >> 9;          // 512 block-cols
  int bx = t & 511;

  u32 pk[3][3][BB][4];      // [r][colOff][b][chpair]
  #pragma unroll
  for (int b = 0; b < BB; ++b)
    #pragma unroll
    for (int j = 0; j < 4; ++j) {
      const float* c0 = x + (size_t)(b * CIN + 2 * j    ) * NPIX;
      const float* c1 = x + (size_t)(b * CIN + 2 * j + 1) * NPIX;
      #pragma unroll
      for (int r = 0; r < 3; ++r) {
        int row = min(2 * by + r, HH - 1);
        int i1 = min(bx + 1, WW / 2 - 1);
        const float2* p0 = (const float2*)(c0 + (size_t)row * WW);
        const float2* p1 = (const float2*)(c1 + (size_t)row * WW);
        float2 a0 = p0[bx], a1 = p0[i1];
        float2 b0 = p1[bx], b1 = p1[i1];
        pk[r][0][b][j] = f2bf(a0.x) | (f2bf(b0.x) << 16);
        pk[r][1][b][j] = f2bf(a0.y) | (f2bf(b0.y) << 16);
        pk[r][2][b][j] = f2bf(a1.x) | (f2bf(b1.x) << 16);
      }
    }

  #pragma unroll
  for (int pyp = 0; pyp < 2; ++pyp)
    #pragma unroll
    for (int pxp = 0; pxp < 2; ++pxp)
      #pragma unroll
      for (int b = 0; b < BB; ++b) {
        u32 base = ((u32)(pyp * 2 + pxp) << 20)
                 + ((u32)(by * 512 + bx) * 2 + (u32)b) * 4;
        #pragma unroll
        for (int d = 0; d < 4; ++d) {
          int dy = d >> 1, dx = d & 1;
          uint4 v;
          v.x = pk[pyp + dy][pxp + dx][b][0];
          v.y = pk[pyp + dy][pxp + dx][b][1];
          v.z = pk[pyp + dy][pxp + dx][b][2];
          v.w = pk[pyp + dy][pxp + dx][b][3];
          xt4[base + d] = v;
        }
      }
}

// One thread = one (pixel,batch). FULL 9-deep prefetch: all 36 gather loads
// issued before any consume; sched_barrier fences keep the order.
__global__ __launch_bounds__(256) void mconv5_k(const uint4* __restrict__ xt4,
                                                const float* __restrict__ sm,
                                                const float* __restrict__ weight,
                                                const float* __restrict__ bias,
                                                float* __restrict__ out) {
  __shared__ float sml[128 * KK * 2];
  __shared__ float wlds[KK * CIN * COUT];          // [k][c][o]

  int tid = threadIdx.x;
  {
    const f32x4* g = (const f32x4*)(sm + (size_t)blockIdx.x * 128 * KK * 2);
    f32x4* l = (f32x4*)sml;
    for (int i = tid; i < 128 * KK * 2 / 4; i += 256) l[i] = g[i];
  }
  for (int i = tid; i < KK * CIN * COUT; i += 256) {
    int k = i >> 7, c = (i >> 4) & 7, o = i & 15;
    wlds[i] = weight[(o * CIN + c) * KK + k];
  }
  __syncthreads();

  const int pl = tid & 127;
  const int b  = tid >> 7;
  const int p  = blockIdx.x * 128 + pl;

  float acc[COUT];
  #pragma unroll
  for (int o = 0; o < COUT; ++o) acc[o] = bias[o];

  auto LOADK = [&](int k, uint4 (&v)[4]) {
    float2 s = ((const float2*)sml)[pl * KK + k];
    int x0 = min(max((int)floorf(s.x), 0), WW - 2);
    int y0 = min(max((int)floorf(s.y), 0), HH - 2);
    u32 idx = ((u32)((y0 & 1) * 2 + (x0 & 1)) << 20)
            + ((u32)((y0 >> 1) * 512 + (x0 >> 1)) * 2 + (u32)b) * 4;
    v[0] = xt4[idx];     v[1] = xt4[idx + 1];
    v[2] = xt4[idx + 2]; v[3] = xt4[idx + 3];
  };

  auto CONS = [&](int k, uint4 (&v)[4]) {
    float2 s = ((const float2*)sml)[pl * KK + k];
    float x0f = floorf(s.x), y0f = floorf(s.y);
    float wx = s.x - x0f, wy = s.y - y0f;
    float w00 = (1.f - wy) * (1.f - wx), w01 = (1.f - wy) * wx;
    float w10 = wy * (1.f - wx),         w11 = wy * wx;
    const float4* w4 = (const float4*)&wlds[k * (CIN * COUT)];

    float sv[8];
    #pragma unroll
    for (int j = 0; j < 4; ++j) {
      u32 a00 = comp4(v[0], j), a01 = comp4(v[1], j);
      u32 a10 = comp4(v[2], j), a11 = comp4(v[3], j);
      sv[2*j]   = w00*bflo(a00) + w01*bflo(a01) + w10*bflo(a10) + w11*bflo(a11);
      sv[2*j+1] = w00*bfhi(a00) + w01*bfhi(a01) + w10*bfhi(a10) + w11*bfhi(a11);
    }
    #pragma unroll
    for (int c = 0; c < 8; ++c) {
      float s0 = sv[c];
      #pragma unroll
      for (int og = 0; og < 4; ++og) {
        float4 wv = w4[c * 4 + og];
        acc[og*4+0] += s0 * wv.x; acc[og*4+1] += s0 * wv.y;
        acc[og*4+2] += s0 * wv.z; acc[og*4+3] += s0 * wv.w;
      }
    }
  };

  uint4 v0[4], v1[4], v2[4], v3[4], v4[4], v5[4], v6[4], v7[4], v8[4];
  LOADK(0, v0); LOADK(1, v1); LOADK(2, v2);
  LOADK(3, v3); LOADK(4, v4); LOADK(5, v5);
  LOADK(6, v6); LOADK(7, v7); LOADK(8, v8);
  SB();
  CONS(0, v0); SB();
  CONS(1, v1); SB();
  CONS(2, v2); SB();
  CONS(3, v3); SB();
  CONS(4, v4); SB();
  CONS(5, v5); SB();
  CONS(6, v6); SB();
  CONS(7, v7); SB();
  CONS(8, v8);

  #pragma unroll
  for (int o = 0; o < COUT; ++o)
    __builtin_nontemporal_store(acc[o], &out[(size_t)(b * COUT + o) * NPIX + p]);
}

// fallback if workspace too small: gather directly from fp32 x [B][C][H][W]
__global__ __launch_bounds__(256) void mconv_direct_k(const float* __restrict__ x,
                                                      const float* __restrict__ sm,
                                                      const float* __restrict__ weight,
                                                      const float* __restrict__ bias,
                                                      float* __restrict__ out) {
  __shared__ float wlds[KK * CIN * COUT];
  int tid = threadIdx.x;
  for (int i = tid; i < KK * CIN * COUT; i += 256) {
    int k = i >> 7, c = (i >> 4) & 7, o = i & 15;
    wlds[i] = weight[(o * CIN + c) * KK + k];
  }
  __syncthreads();

  int p = blockIdx.x * 256 + tid;
  if (p >= NPIX) return;

  float acc[2][COUT];
  #pragma unroll
  for (int o = 0; o < COUT; ++o) { float bv = bias[o]; acc[0][o] = bv; acc[1][o] = bv; }

  const float2* smp = (const float2*)sm;

  for (int k = 0; k < KK; ++k) {
    float2 s = smp[(size_t)p * KK + k];
    float x0f = floorf(s.x), y0f = floorf(s.y);
    float wx = s.x - x0f, wy = s.y - y0f;
    int x0 = min(max((int)x0f, 0), WW - 1);
    int y0 = min(max((int)y0f, 0), HH - 1);
    int x1 = min(x0 + 1, WW - 1), y1 = min(y0 + 1, HH - 1);
    float w00 = (1.f - wy) * (1.f - wx), w01 = (1.f - wy) * wx;
    float w10 = wy * (1.f - wx),         w11 = wy * wx;

    float sv[2][8];
    #pragma unroll
    for (int b = 0; b < 2; ++b) {
      #pragma unroll
      for (int c = 0; c < 8; ++c) {
        const float* xp = x + (size_t)(b * CIN + c) * NPIX;
        float v00 = xp[y0 * WW + x0], v01 = xp[y0 * WW + x1];
        float v10 = xp[y1 * WW + x0], v11 = xp[y1 * WW + x1];
        sv[b][c] = w00 * v00 + w01 * v01 + w10 * v10 + w11 * v11;
      }
    }

    const float4* w4 = (const float4*)&wlds[k * (CIN * COUT)];
    #pragma unroll
    for (int c = 0; c < 8; ++c) {
      float s0 = sv[0][c], s1 = sv[1][c];
      #pragma unroll
      for (int og = 0; og < 4; ++og) {
        float4 wv = w4[c * 4 + og];
        acc[0][og*4+0] += s0 * wv.x; acc[1][og*4+0] += s1 * wv.x;
        acc[0][og*4+1] += s0 * wv.y; acc[1][og*4+1] += s1 * wv.y;
        acc[0][og*4+2] += s0 * wv.z; acc[1][og*4+2] += s1 * wv.z;
        acc[0][og*4+3] += s0 * wv.w; acc[1][og*4+3] += s1 * wv.w;
      }
    }
  }

  #pragma unroll
  for (int b = 0; b < 2; ++b)
    #pragma unroll
    for (int o = 0; o < COUT; ++o)
      out[(size_t)(b * COUT + o) * NPIX + p] = acc[b][o];
}

extern "C" void kernel_launch(void* const* d_in, const int* in_sizes, int n_in,
                              void* d_out, int out_size, void* d_ws, size_t ws_size,
                              hipStream_t stream) {
  const float* x      = (const float*)d_in[0];
  const float* sm     = (const float*)d_in[1];
  const float* weight = (const float*)d_in[2];
  const float* bias   = (const float*)d_in[3];
  float* out = (float*)d_out;

  const size_t oneCopy = (size_t)COPY4 * sizeof(uint4);   // 16 MB
  uint4* xt4 = (uint4*)d_ws;
  if (ws_size >= 4 * oneCopy) {
    hipLaunchKernelGGL(xpose3b_k, dim3((HH / 2) * (WW / 2) / 256), dim3(256), 0,
                       stream, x, xt4);
    hipLaunchKernelGGL(mconv5_k, dim3(NPIX / 128), dim3(256), 0, stream,
                       xt4, sm, weight, bias, out);
  } else {
    hipLaunchKernelGGL(mconv_direct_k, dim3((NPIX + 255) / 256), dim3(256), 0, stream,
                       x, sm, weight, bias, out);
  }
}

// Round 8
// 141.614 us; speedup vs baseline: 1.7746x; 1.1727x over previous
//
#include <hip/hip_runtime.h>

#define BB   2
#define CIN  8
#define COUT 16
#define HH   512
#define WW   1024
#define KK   9
#define NPIX (HH*WW)
#define COPY4 (1u << 20)   // uint4 elements per 16MB copy

typedef unsigned int u32;
typedef float f32x4 __attribute__((ext_vector_type(4)));
typedef float f32x2 __attribute__((ext_vector_type(2)));

#define SB() __builtin_amdgcn_sched_barrier(0)

// fp32 -> bf16 bits, round-nearest-even
__device__ __forceinline__ u32 f2bf(float f) {
  u32 u = __float_as_uint(f);
  return (u + 0x7fffu + ((u >> 16) & 1u)) >> 16;
}
__device__ __forceinline__ float bflo(u32 u) { return __uint_as_float(u << 16); }
__device__ __forceinline__ float bfhi(u32 u) { return __uint_as_float(u & 0xffff0000u); }
__device__ __forceinline__ u32 comp4(uint4 v, int j) {
  return j == 0 ? v.x : j == 1 ? v.y : j == 2 ? v.z : v.w;
}

// ============ 4-copy 2D-parity layout ============
// copy (pyp,pxp): 2x2-pixel blocks starting at rows 2*by+pyp, cols 2*bx+pxp.
// uint4 index = (pyp*2+pxp)<<20 + ((by*512+bx)*2 + b)*4 + dy*2 + dx
// One 64B block = 2y x 2x x 8ch bf16 of one batch.

// One thread per (by,bx,b): reads its 3x3 fp32 neighborhood for ONE batch,
// writes complete 64B blocks; thread pairs (b=t&1) make 128B-contiguous stores.
__global__ __launch_bounds__(256) void xpose3c_k(const float* __restrict__ x,
                                                 uint4* __restrict__ xt4) {
  int t = blockIdx.x * 256 + threadIdx.x;
  if (t >= (HH / 2) * (WW / 2) * BB) return;
  int b  = t & 1;
  int s  = t >> 1;
  int by = s >> 9;          // 512 block-cols
  int bx = s & 511;

  u32 pk[3][3][4];          // [r][colOff][chpair]
  #pragma unroll
  for (int j = 0; j < 4; ++j) {
    const float* c0 = x + (size_t)(b * CIN + 2 * j    ) * NPIX;
    const float* c1 = x + (size_t)(b * CIN + 2 * j + 1) * NPIX;
    int i1 = min(bx + 1, WW / 2 - 1);
    #pragma unroll
    for (int r = 0; r < 3; ++r) {
      int row = min(2 * by + r, HH - 1);
      const float2* p0 = (const float2*)(c0 + (size_t)row * WW);
      const float2* p1 = (const float2*)(c1 + (size_t)row * WW);
      float2 a0 = p0[bx], a1 = p0[i1];
      float2 b0 = p1[bx], b1 = p1[i1];
      pk[r][0][j] = f2bf(a0.x) | (f2bf(b0.x) << 16);
      pk[r][1][j] = f2bf(a0.y) | (f2bf(b0.y) << 16);
      pk[r][2][j] = f2bf(a1.x) | (f2bf(b1.x) << 16);
    }
  }

  #pragma unroll
  for (int pyp = 0; pyp < 2; ++pyp)
    #pragma unroll
    for (int pxp = 0; pxp < 2; ++pxp) {
      u32 base = ((u32)(pyp * 2 + pxp) << 20)
               + ((u32)(by * 512 + bx) * 2 + (u32)b) * 4;
      #pragma unroll
      for (int d = 0; d < 4; ++d) {
        int dy = d >> 1, dx = d & 1;
        uint4 v;
        v.x = pk[pyp + dy][pxp + dx][0];
        v.y = pk[pyp + dy][pxp + dx][1];
        v.z = pk[pyp + dy][pxp + dx][2];
        v.w = pk[pyp + dy][pxp + dx][3];
        xt4[base + d] = v;
      }
    }
}

// One thread = one (pixel,batch). Depth-4 pipeline (RA-holdable) + packed f32 FMA.
__global__ __launch_bounds__(256) void mconv6_k(const uint4* __restrict__ xt4,
                                                const float* __restrict__ sm,
                                                const float* __restrict__ weight,
                                                const float* __restrict__ bias,
                                                float* __restrict__ out) {
  __shared__ float sml[128 * KK * 2];
  __shared__ float wlds[KK * CIN * COUT];          // [k][c][o]

  int tid = threadIdx.x;
  {
    const f32x4* g = (const f32x4*)(sm + (size_t)blockIdx.x * 128 * KK * 2);
    f32x4* l = (f32x4*)sml;
    for (int i = tid; i < 128 * KK * 2 / 4; i += 256) l[i] = g[i];
  }
  for (int i = tid; i < KK * CIN * COUT; i += 256) {
    int k = i >> 7, c = (i >> 4) & 7, o = i & 15;
    wlds[i] = weight[(o * CIN + c) * KK + k];
  }
  __syncthreads();

  const int pl = tid & 127;
  const int b  = tid >> 7;
  const int p  = blockIdx.x * 128 + pl;

  f32x2 acc2[8];
  #pragma unroll
  for (int o2 = 0; o2 < 8; ++o2) { acc2[o2][0] = bias[2*o2]; acc2[o2][1] = bias[2*o2+1]; }

  const float2* smp = (const float2*)sml + pl * KK;

  auto LOADK = [&](int k, uint4 (&v)[4]) {
    float2 s = smp[k];
    int x0 = min(max((int)floorf(s.x), 0), WW - 2);
    int y0 = min(max((int)floorf(s.y), 0), HH - 2);
    u32 idx = ((u32)((y0 & 1) * 2 + (x0 & 1)) << 20)
            + ((u32)((y0 >> 1) * 512 + (x0 >> 1)) * 2 + (u32)b) * 4;
    v[0] = xt4[idx];     v[1] = xt4[idx + 1];
    v[2] = xt4[idx + 2]; v[3] = xt4[idx + 3];
  };

  auto CONS = [&](int k, uint4 (&v)[4]) {
    float2 s = smp[k];
    float x0f = floorf(s.x), y0f = floorf(s.y);
    float wx = s.x - x0f, wy = s.y - y0f;
    float w00 = (1.f - wy) * (1.f - wx), w01 = (1.f - wy) * wx;
    float w10 = wy * (1.f - wx),         w11 = wy * wx;
    const float4* w4 = (const float4*)&wlds[k * (CIN * COUT)];

    float sv[8];
    #pragma unroll
    for (int j = 0; j < 4; ++j) {
      u32 a00 = comp4(v[0], j), a01 = comp4(v[1], j);
      u32 a10 = comp4(v[2], j), a11 = comp4(v[3], j);
      sv[2*j]   = w00*bflo(a00) + w01*bflo(a01) + w10*bflo(a10) + w11*bflo(a11);
      sv[2*j+1] = w00*bfhi(a00) + w01*bfhi(a01) + w10*bfhi(a10) + w11*bfhi(a11);
    }
    #pragma unroll
    for (int c = 0; c < 8; ++c) {
      float s0 = sv[c];
      #pragma unroll
      for (int og = 0; og < 4; ++og) {
        float4 wv = w4[c * 4 + og];
        f32x2 wlo; wlo[0] = wv.x; wlo[1] = wv.y;
        f32x2 whi; whi[0] = wv.z; whi[1] = wv.w;
        acc2[og*2]   += wlo * s0;     // v_pk_fma_f32
        acc2[og*2+1] += whi * s0;
      }
    }
  };

  uint4 va[4], vb[4], vc[4], vd[4];
  LOADK(0, va); LOADK(1, vb); LOADK(2, vc); LOADK(3, vd); SB();
  CONS(0, va);  SB(); LOADK(4, va); SB();
  CONS(1, vb);  SB(); LOADK(5, vb); SB();
  CONS(2, vc);  SB(); LOADK(6, vc); SB();
  CONS(3, vd);  SB(); LOADK(7, vd); SB();
  CONS(4, va);  SB(); LOADK(8, va); SB();
  CONS(5, vb);  SB();
  CONS(6, vc);  SB();
  CONS(7, vd);  SB();
  CONS(8, va);

  #pragma unroll
  for (int o2 = 0; o2 < 8; ++o2) {
    __builtin_nontemporal_store(acc2[o2][0], &out[(size_t)(b * COUT + 2*o2    ) * NPIX + p]);
    __builtin_nontemporal_store(acc2[o2][1], &out[(size_t)(b * COUT + 2*o2 + 1) * NPIX + p]);
  }
}

// fallback if workspace too small: gather directly from fp32 x [B][C][H][W]
__global__ __launch_bounds__(256) void mconv_direct_k(const float* __restrict__ x,
                                                      const float* __restrict__ sm,
                                                      const float* __restrict__ weight,
                                                      const float* __restrict__ bias,
                                                      float* __restrict__ out) {
  __shared__ float wlds[KK * CIN * COUT];
  int tid = threadIdx.x;
  for (int i = tid; i < KK * CIN * COUT; i += 256) {
    int k = i >> 7, c = (i >> 4) & 7, o = i & 15;
    wlds[i] = weight[(o * CIN + c) * KK + k];
  }
  __syncthreads();

  int p = blockIdx.x * 256 + tid;
  if (p >= NPIX) return;

  float acc[2][COUT];
  #pragma unroll
  for (int o = 0; o < COUT; ++o) { float bv = bias[o]; acc[0][o] = bv; acc[1][o] = bv; }

  const float2* smp = (const float2*)sm;

  for (int k = 0; k < KK; ++k) {
    float2 s = smp[(size_t)p * KK + k];
    float x0f = floorf(s.x), y0f = floorf(s.y);
    float wx = s.x - x0f, wy = s.y - y0f;
    int x0 = min(max((int)x0f, 0), WW - 1);
    int y0 = min(max((int)y0f, 0), HH - 1);
    int x1 = min(x0 + 1, WW - 1), y1 = min(y0 + 1, HH - 1);
    float w00 = (1.f - wy) * (1.f - wx), w01 = (1.f - wy) * wx;
    float w10 = wy * (1.f - wx),         w11 = wy * wx;

    float sv[2][8];
    #pragma unroll
    for (int b = 0; b < 2; ++b) {
      #pragma unroll
      for (int c = 0; c < 8; ++c) {
        const float* xp = x + (size_t)(b * CIN + c) * NPIX;
        float v00 = xp[y0 * WW + x0], v01 = xp[y0 * WW + x1];
        float v10 = xp[y1 * WW + x0], v11 = xp[y1 * WW + x1];
        sv[b][c] = w00 * v00 + w01 * v01 + w10 * v10 + w11 * v11;
      }
    }

    const float4* w4 = (const float4*)&wlds[k * (CIN * COUT)];
    #pragma unroll
    for (int c = 0; c < 8; ++c) {
      float s0 = sv[0][c], s1 = sv[1][c];
      #pragma unroll
      for (int og = 0; og < 4; ++og) {
        float4 wv = w4[c * 4 + og];
        acc[0][og*4+0] += s0 * wv.x; acc[1][og*4+0] += s1 * wv.x;
        acc[0][og*4+1] += s0 * wv.y; acc[1][og*4+1] += s1 * wv.y;
        acc[0][og*4+2] += s0 * wv.z; acc[1][og*4+2] += s1 * wv.z;
        acc[0][og*4+3] += s0 * wv.w; acc[1][og*4+3] += s1 * wv.w;
      }
    }
  }

  #pragma unroll
  for (int b = 0; b < 2; ++b)
    #pragma unroll
    for (int o = 0; o < COUT; ++o)
      out[(size_t)(b * COUT + o) * NPIX + p] = acc[b][o];
}

extern "C" void kernel_launch(void* const* d_in, const int* in_sizes, int n_in,
                              void* d_out, int out_size, void* d_ws, size_t ws_size,
                              hipStream_t stream) {
  const float* x      = (const float*)d_in[0];
  const float* sm     = (const float*)d_in[1];
  const float* weight = (const float*)d_in[2];
  const float* bias   = (const float*)d_in[3];
  float* out = (float*)d_out;

  const size_t oneCopy = (size_t)COPY4 * sizeof(uint4);   // 16 MB
  uint4* xt4 = (uint4*)d_ws;
  if (ws_size >= 4 * oneCopy) {
    hipLaunchKernelGGL(xpose3c_k, dim3((HH / 2) * (WW / 2) * BB / 256), dim3(256), 0,
                       stream, x, xt4);
    hipLaunchKernelGGL(mconv6_k, dim3(NPIX / 128), dim3(256), 0, stream,
                       xt4, sm, weight, bias, out);
  } else {
    hipLaunchKernelGGL(mconv_direct_k, dim3((NPIX + 255) / 256), dim3(256), 0, stream,
                       x, sm, weight, bias, out);
  }
}